// Round 1
// baseline (1367.173 us; speedup 1.0000x reference)
//
#include <hip/hip_runtime.h>
#include <hip/hip_bf16.h>

typedef __bf16 bf16_t;
typedef __bf16 bf16x8 __attribute__((ext_vector_type(8)));
typedef float f32x4 __attribute__((ext_vector_type(4)));

#define GLOAD16(gp, lp) __builtin_amdgcn_global_load_lds(                      \
    (const __attribute__((address_space(1))) void*)(gp),                       \
    (__attribute__((address_space(3))) void*)(lp), 16, 0, 0)

// ---------------- cast fp32 -> bf16 (vectorized x8) ----------------
__global__ __launch_bounds__(256) void cast_f32_bf16_k(
    const float* __restrict__ in, bf16_t* __restrict__ out, long n8) {
  long i = (long)blockIdx.x * blockDim.x + threadIdx.x;
  long stride = (long)gridDim.x * blockDim.x;
  for (; i < n8; i += stride) {
    long e = i * 8;
    float4 a = *(const float4*)(in + e);
    float4 b = *(const float4*)(in + e + 4);
    bf16x8 o;
    o[0] = (__bf16)a.x; o[1] = (__bf16)a.y; o[2] = (__bf16)a.z; o[3] = (__bf16)a.w;
    o[4] = (__bf16)b.x; o[5] = (__bf16)b.y; o[6] = (__bf16)b.z; o[7] = (__bf16)b.w;
    *(bf16x8*)(out + e) = o;
  }
}

// ---------------- NT GEMM: C[i,j] = sum_k A[i,k]*B[j,k] (+epilogue) --------
template <int BIAS, bool MUL, bool RES, bool OUTBF16>
__global__ __launch_bounds__(256) void gemm_nt(
    const bf16_t* __restrict__ A, const bf16_t* __restrict__ B,
    const float* __restrict__ bias, const bf16_t* __restrict__ mulm,
    const float* __restrict__ res, float* __restrict__ outf,
    bf16_t* __restrict__ outb, int M, int N, int K) {
  __shared__ bf16_t As[128 * 32];
  __shared__ bf16_t Bs[128 * 32];
  const int tid = threadIdx.x;
  const long row0 = (long)blockIdx.y * 128;
  const long col0 = (long)blockIdx.x * 128;
  const int wid = tid >> 6, lane = tid & 63;
  const int wr = (wid >> 1) * 64;
  const int wc = (wid & 1) * 64;
  const int fr = lane & 15, fq = lane >> 4;
  const int srow = tid >> 2;
  const int scol = (tid & 3) * 8;

  f32x4 acc[4][4] = {};

  const bf16_t* Ag = A + (row0 + srow) * (long)K + scol;
  const bf16_t* Bg = B + (col0 + srow) * (long)K + scol;
  const long k64 = 64L * K;
  bf16_t* ldsA = As + wid * 512;
  bf16_t* ldsB = Bs + wid * 512;

  for (int k0 = 0; k0 < K; k0 += 32) {
    GLOAD16(Ag + k0, ldsA);
    GLOAD16(Ag + k0 + k64, ldsA + 2048);
    GLOAD16(Bg + k0, ldsB);
    GLOAD16(Bg + k0 + k64, ldsB + 2048);
    __syncthreads();
    bf16x8 av[4], bv[4];
#pragma unroll
    for (int i = 0; i < 4; i++)
      av[i] = *(const bf16x8*)(As + (wr + i * 16 + fr) * 32 + fq * 8);
#pragma unroll
    for (int j = 0; j < 4; j++)
      bv[j] = *(const bf16x8*)(Bs + (wc + j * 16 + fr) * 32 + fq * 8);
#pragma unroll
    for (int i = 0; i < 4; i++)
#pragma unroll
      for (int j = 0; j < 4; j++)
        acc[i][j] = __builtin_amdgcn_mfma_f32_16x16x32_bf16(av[i], bv[j],
                                                            acc[i][j], 0, 0, 0);
    __syncthreads();
  }

#pragma unroll
  for (int i = 0; i < 4; i++) {
#pragma unroll
    for (int j = 0; j < 4; j++) {
#pragma unroll
      for (int r = 0; r < 4; r++) {
        long gi = row0 + wr + i * 16 + fq * 4 + r;
        long gj = col0 + wc + j * 16 + fr;
        float v = acc[i][j][r];
        if (BIAS == 1) v += bias[gj];
        if (BIAS == 2) v += bias[gi];
        long idx = gi * (long)N + gj;
        if (MUL) v *= (float)mulm[idx];
        if (RES) v += res[idx];
        if (OUTBF16) outb[idx] = (bf16_t)v;
        else outf[idx] = v;
      }
    }
  }
}

// ---------------- row softmax over 8192 cols, bf16 in-place ----------------
__global__ __launch_bounds__(256) void softmax_bf16_inplace(
    bf16_t* __restrict__ buf) {
  const long row = blockIdx.x;
  bf16_t* p = buf + row * 8192;
  const int t = threadIdx.x;
  float v[32];
#pragma unroll
  for (int i = 0; i < 4; i++) {
    bf16x8 raw = *(const bf16x8*)(p + t * 32 + i * 8);
#pragma unroll
    for (int j = 0; j < 8; j++) v[i * 8 + j] = (float)raw[j];
  }
  float m = -1e30f;
#pragma unroll
  for (int i = 0; i < 32; i++) m = fmaxf(m, v[i]);
  for (int off = 32; off; off >>= 1) m = fmaxf(m, __shfl_xor(m, off, 64));
  __shared__ float redm[4], reds[4];
  if ((t & 63) == 0) redm[t >> 6] = m;
  __syncthreads();
  m = fmaxf(fmaxf(redm[0], redm[1]), fmaxf(redm[2], redm[3]));
  float s = 0.f;
#pragma unroll
  for (int i = 0; i < 32; i++) {
    v[i] = __expf(v[i] - m);
    s += v[i];
  }
  for (int off = 32; off; off >>= 1) s += __shfl_xor(s, off, 64);
  if ((t & 63) == 0) reds[t >> 6] = s;
  __syncthreads();
  s = reds[0] + reds[1] + reds[2] + reds[3];
  float inv = 1.0f / s;
#pragma unroll
  for (int i = 0; i < 4; i++) {
    bf16x8 o;
#pragma unroll
    for (int j = 0; j < 8; j++) o[j] = (bf16_t)(v[i * 8 + j] * inv);
    *(bf16x8*)(p + t * 32 + i * 8) = o;
  }
}

// --------- row softmax: bf16 logits in, fp32 out + bf16 in-place ----------
__global__ __launch_bounds__(256) void softmax_f_k(bf16_t* __restrict__ fm,
                                                   float* __restrict__ outf) {
  const long row = blockIdx.x;
  bf16_t* p = fm + row * 8192;
  float* q = outf + row * 8192;
  const int t = threadIdx.x;
  float v[32];
#pragma unroll
  for (int i = 0; i < 4; i++) {
    bf16x8 raw = *(const bf16x8*)(p + t * 32 + i * 8);
#pragma unroll
    for (int j = 0; j < 8; j++) v[i * 8 + j] = (float)raw[j];
  }
  float m = -1e30f;
#pragma unroll
  for (int i = 0; i < 32; i++) m = fmaxf(m, v[i]);
  for (int off = 32; off; off >>= 1) m = fmaxf(m, __shfl_xor(m, off, 64));
  __shared__ float redm[4], reds[4];
  if ((t & 63) == 0) redm[t >> 6] = m;
  __syncthreads();
  m = fmaxf(fmaxf(redm[0], redm[1]), fmaxf(redm[2], redm[3]));
  float s = 0.f;
#pragma unroll
  for (int i = 0; i < 32; i++) {
    v[i] = __expf(v[i] - m);
    s += v[i];
  }
  for (int off = 32; off; off >>= 1) s += __shfl_xor(s, off, 64);
  if ((t & 63) == 0) reds[t >> 6] = s;
  __syncthreads();
  s = reds[0] + reds[1] + reds[2] + reds[3];
  float inv = 1.0f / s;
#pragma unroll
  for (int i = 0; i < 8; i++) {
    float4 o;
    o.x = v[i * 4 + 0] * inv;
    o.y = v[i * 4 + 1] * inv;
    o.z = v[i * 4 + 2] * inv;
    o.w = v[i * 4 + 3] * inv;
    *(float4*)(q + t * 32 + i * 4) = o;
  }
#pragma unroll
  for (int i = 0; i < 4; i++) {
    bf16x8 o;
#pragma unroll
    for (int j = 0; j < 8; j++) o[j] = (bf16_t)(v[i * 8 + j] * inv);
    *(bf16x8*)(p + t * 32 + i * 8) = o;
  }
}

// ---------------------------------------------------------------------------
extern "C" void kernel_launch(void* const* d_in, const int* in_sizes, int n_in,
                              void* d_out, int out_size, void* d_ws,
                              size_t ws_size, hipStream_t stream) {
  const int N = 8192, C = 2048, IC = 1024;
  const float* x = (const float*)d_in[0];
  const float* theta_b = (const float*)d_in[2];
  const float* theta_w = (const float*)d_in[1];
  const float* phi_w = (const float*)d_in[3];
  const float* phi_b = (const float*)d_in[4];
  const float* g_w = (const float*)d_in[5];
  const float* g_b = (const float*)d_in[6];
  const float* W_w = (const float*)d_in[7];
  const float* W_b = (const float*)d_in[8];
  const float* mask_w = (const float*)d_in[9];
  const float* mask_b = (const float*)d_in[10];

  float* z_out = (float*)d_out;            // [N,C] fp32
  float* f_out = z_out + (long)N * C;      // [N,N] fp32

  // d_out-hosted scratch (dead before those regions' final writes):
  bf16_t* ML = (bf16_t*)f_out;             // [N,N] bf16 mask logits -> mask
  bf16_t* th16 = (bf16_t*)z_out;           // [N,IC]
  bf16_t* ph16 = th16 + (long)N * IC;      // [N,IC]
  bf16_t* gT16 = ph16 + (long)N * IC;      // [IC,N]

  char* w = (char*)d_ws;
  bf16_t* xb = (bf16_t*)w;      w += (long)N * C * 2;
  bf16_t* mwb = (bf16_t*)w;     w += (long)N * C * 2;
  bf16_t* thwb = (bf16_t*)w;    w += (long)IC * C * 2;
  bf16_t* phwb = (bf16_t*)w;    w += (long)IC * C * 2;
  bf16_t* gwb = (bf16_t*)w;     w += (long)IC * C * 2;
  bf16_t* Wwb = (bf16_t*)w;     w += (long)C * IC * 2;
  bf16_t* fm = (bf16_t*)w;      w += (long)N * N * 2;   // f*mask logits -> P
  bf16_t* y16 = (bf16_t*)w;     w += (long)N * IC * 2;

  cast_f32_bf16_k<<<8192, 256, 0, stream>>>(x, xb, (long)N * C / 8);
  cast_f32_bf16_k<<<8192, 256, 0, stream>>>(mask_w, mwb, (long)N * C / 8);
  cast_f32_bf16_k<<<1024, 256, 0, stream>>>(theta_w, thwb, (long)IC * C / 8);
  cast_f32_bf16_k<<<1024, 256, 0, stream>>>(phi_w, phwb, (long)IC * C / 8);
  cast_f32_bf16_k<<<1024, 256, 0, stream>>>(g_w, gwb, (long)IC * C / 8);
  cast_f32_bf16_k<<<1024, 256, 0, stream>>>(W_w, Wwb, (long)C * IC / 8);

  gemm_nt<1, false, false, true><<<dim3(IC / 128, N / 128), 256, 0, stream>>>(
      xb, thwb, theta_b, nullptr, nullptr, nullptr, th16, N, IC, C);
  gemm_nt<1, false, false, true><<<dim3(IC / 128, N / 128), 256, 0, stream>>>(
      xb, phwb, phi_b, nullptr, nullptr, nullptr, ph16, N, IC, C);
  gemm_nt<2, false, false, true><<<dim3(N / 128, IC / 128), 256, 0, stream>>>(
      gwb, xb, g_b, nullptr, nullptr, nullptr, gT16, IC, N, C);
  gemm_nt<1, false, false, true><<<dim3(N / 128, N / 128), 256, 0, stream>>>(
      xb, mwb, mask_b, nullptr, nullptr, nullptr, ML, N, N, C);
  softmax_bf16_inplace<<<N, 256, 0, stream>>>(ML);
  gemm_nt<0, true, false, true><<<dim3(N / 128, N / 128), 256, 0, stream>>>(
      th16, ph16, nullptr, ML, nullptr, nullptr, fm, N, N, IC);
  softmax_f_k<<<N, 256, 0, stream>>>(fm, f_out);
  gemm_nt<0, false, false, true><<<dim3(IC / 128, N / 128), 256, 0, stream>>>(
      fm, gT16, nullptr, nullptr, nullptr, nullptr, y16, N, IC, N);
  gemm_nt<1, false, true, false><<<dim3(C / 128, N / 128), 256, 0, stream>>>(
      y16, Wwb, W_b, nullptr, x, z_out, nullptr, N, C, IC);
}

// Round 2
// 1217.360 us; speedup vs baseline: 1.1231x; 1.1231x over previous
//
#include <hip/hip_runtime.h>
#include <hip/hip_bf16.h>

typedef __bf16 bf16_t;
typedef __bf16 bf16x8 __attribute__((ext_vector_type(8)));
typedef float f32x4 __attribute__((ext_vector_type(4)));

#define GLOAD16(gp, lp) __builtin_amdgcn_global_load_lds(                      \
    (const __attribute__((address_space(1))) void*)(gp),                       \
    (__attribute__((address_space(3))) void*)(lp), 16, 0, 0)
#define BARRIER() asm volatile("s_barrier" ::: "memory")
#define LGKM0()                                                                \
  do {                                                                         \
    asm volatile("s_waitcnt lgkmcnt(0)" ::: "memory");                         \
    __builtin_amdgcn_sched_barrier(0);                                         \
  } while (0)

// ---------------- cast fp32 -> bf16 (vectorized x8) ----------------
__global__ __launch_bounds__(256) void cast_f32_bf16_k(
    const float* __restrict__ in, bf16_t* __restrict__ out, long n8) {
  long i = (long)blockIdx.x * blockDim.x + threadIdx.x;
  long stride = (long)gridDim.x * blockDim.x;
  for (; i < n8; i += stride) {
    long e = i * 8;
    float4 a = *(const float4*)(in + e);
    float4 b = *(const float4*)(in + e + 4);
    bf16x8 o;
    o[0] = (__bf16)a.x; o[1] = (__bf16)a.y; o[2] = (__bf16)a.z; o[3] = (__bf16)a.w;
    o[4] = (__bf16)b.x; o[5] = (__bf16)b.y; o[6] = (__bf16)b.z; o[7] = (__bf16)b.w;
    *(bf16x8*)(out + e) = o;
  }
}

// ============ 256x256-tile 8-wave GEMM, BK=32, 4-deep counted-vmcnt pipeline
// C[i,j] = sum_k A[i,k]*B[j,k]; M,N mult of 256, K mult of 32, K/32 >= 4.
// LDS: 4 buffers x (A 16KB + B 16KB) = 128 KiB. 1 block/CU, 512 threads.
template <int VM, bool ST>
__device__ __forceinline__ void kstep256(
    int t, char* lds, const int (&aoff)[8], const int (&boff)[4],
    const bf16_t* As0, const bf16_t* As1, const bf16_t* Bs0,
    const bf16_t* Bs1, int dst0, int dst1, f32x4 (&acc)[8][4]) {
  char* buf = lds + (t & 3) * 32768;
  char* nbuf = lds + ((t + 3) & 3) * 32768;
  bf16x8 av[8], bv[4];
  // ---- phase 1: 8 ds_read + stage A(t+3) + 16 MFMA (row frags 0..3)
#pragma unroll
  for (int i = 0; i < 4; ++i) av[i] = *(const bf16x8*)(buf + aoff[i]);
#pragma unroll
  for (int j = 0; j < 4; ++j) bv[j] = *(const bf16x8*)(buf + 16384 + boff[j]);
  if (ST) {
    GLOAD16(As0 + (long)(t + 3) * 32, nbuf + dst0);
    GLOAD16(As1 + (long)(t + 3) * 32, nbuf + dst1);
  }
  BARRIER();
  LGKM0();
  __builtin_amdgcn_s_setprio(1);
#pragma unroll
  for (int i = 0; i < 4; ++i)
#pragma unroll
    for (int j = 0; j < 4; ++j)
      acc[i][j] = __builtin_amdgcn_mfma_f32_16x16x32_bf16(av[i], bv[j],
                                                          acc[i][j], 0, 0, 0);
  __builtin_amdgcn_s_setprio(0);
  BARRIER();
  // ---- phase 2: 4 ds_read + stage B(t+3) + counted vmcnt + 16 MFMA (4..7)
#pragma unroll
  for (int i = 4; i < 8; ++i) av[i] = *(const bf16x8*)(buf + aoff[i]);
  if (ST) {
    GLOAD16(Bs0 + (long)(t + 3) * 32, nbuf + 16384 + dst0);
    GLOAD16(Bs1 + (long)(t + 3) * 32, nbuf + 16384 + dst1);
  }
  if (VM == 8) asm volatile("s_waitcnt vmcnt(8)" ::: "memory");
  else if (VM == 4) asm volatile("s_waitcnt vmcnt(4)" ::: "memory");
  else if (VM == 0) asm volatile("s_waitcnt vmcnt(0)" ::: "memory");
  BARRIER();
  LGKM0();
  __builtin_amdgcn_s_setprio(1);
#pragma unroll
  for (int i = 4; i < 8; ++i)
#pragma unroll
    for (int j = 0; j < 4; ++j)
      acc[i][j] = __builtin_amdgcn_mfma_f32_16x16x32_bf16(av[i], bv[j],
                                                          acc[i][j], 0, 0, 0);
  __builtin_amdgcn_s_setprio(0);
  BARRIER();
}

template <int BIAS, bool MUL>
__global__ __launch_bounds__(512, 2) void gemm256(
    const bf16_t* __restrict__ A, const bf16_t* __restrict__ B,
    const float* __restrict__ bias, const bf16_t* __restrict__ mulm,
    bf16_t* __restrict__ out, int M, int N, int K) {
  __shared__ __align__(1024) char lds[131072];
  const int tid = threadIdx.x;
  const int gx = N >> 8;
  int bid = blockIdx.y * gx + blockIdx.x;
  const int nwg = gridDim.x * gridDim.y;        // multiple of 8 for our shapes
  const int cpx = nwg >> 3;
  bid = (bid & 7) * cpx + (bid >> 3);           // XCD-aware bijective swizzle
  const long row0 = (long)(bid / gx) * 256;
  const long col0 = (long)(bid % gx) * 256;

  const int w = tid >> 6, lane = tid & 63;
  const int wm = w >> 2, wn = w & 3;            // 2M x 4N waves
  const int fr = lane & 15, fq = lane >> 4;

  // LDS byte offsets of this thread's fragments (row stride 64B, BK=32)
  int aoff[8], boff[4];
#pragma unroll
  for (int i = 0; i < 8; ++i)
    aoff[i] = (wm * 128 + i * 16 + fr) * 64 + fq * 16;
#pragma unroll
  for (int j = 0; j < 4; ++j)
    boff[j] = (wn * 64 + j * 16 + fr) * 64 + fq * 16;

  // staging: per wave 2 gloads per matrix per tile; linear LDS dest
  const int p0 = w * 1024 + lane * 16;          // physical byte in 16KB tile
  const int p1 = p0 + 8192;
  const int r0 = p0 >> 6, r1 = p1 >> 6;
  const int k0b = p0 & 63, k1b = p1 & 63;
  const bf16_t* As0 = A + (row0 + r0) * (long)K + (k0b >> 1);
  const bf16_t* As1 = A + (row0 + r1) * (long)K + (k1b >> 1);
  const bf16_t* Bs0 = B + (col0 + r0) * (long)K + (k0b >> 1);
  const bf16_t* Bs1 = B + (col0 + r1) * (long)K + (k1b >> 1);
  const int dst0 = w * 1024;                    // wave-uniform LDS dest base
  const int dst1 = dst0 + 8192;

  f32x4 acc[8][4] = {};
  const int NT = K >> 5;

  // prologue: stage tiles 0,1,2 (12 VMEM/wave), wait for tile 0 (vmcnt 8)
#pragma unroll
  for (int t = 0; t < 3; ++t) {
    char* buf = lds + t * 32768;
    GLOAD16(As0 + (long)t * 32, buf + dst0);
    GLOAD16(As1 + (long)t * 32, buf + dst1);
    GLOAD16(Bs0 + (long)t * 32, buf + 16384 + dst0);
    GLOAD16(Bs1 + (long)t * 32, buf + 16384 + dst1);
  }
  asm volatile("s_waitcnt vmcnt(8)" ::: "memory");
  BARRIER();

  int t = 0;
  for (; t < NT - 3; ++t)
    kstep256<8, true>(t, lds, aoff, boff, As0, As1, Bs0, Bs1, dst0, dst1, acc);
  kstep256<4, false>(t, lds, aoff, boff, As0, As1, Bs0, Bs1, dst0, dst1, acc); ++t;
  kstep256<0, false>(t, lds, aoff, boff, As0, As1, Bs0, Bs1, dst0, dst1, acc); ++t;
  kstep256<-1, false>(t, lds, aoff, boff, As0, As1, Bs0, Bs1, dst0, dst1, acc);

  // epilogue: C/D layout col=lane&15, row=(lane>>4)*4+r
#pragma unroll
  for (int i = 0; i < 8; ++i)
#pragma unroll
    for (int j = 0; j < 4; ++j)
#pragma unroll
      for (int r = 0; r < 4; ++r) {
        long gi = row0 + wm * 128 + i * 16 + fq * 4 + r;
        long gj = col0 + wn * 64 + j * 16 + fr;
        float v = acc[i][j][r];
        if (BIAS == 1) v += bias[gj];
        long idx = gi * (long)N + gj;
        if (MUL) v *= (float)mulm[idx];
        out[idx] = (bf16_t)v;
      }
}

// ---------------- NT GEMM (m97 128x128) for the small/odd-shaped GEMMs -----
template <int BIAS, bool MUL, bool RES, bool OUTBF16>
__global__ __launch_bounds__(256) void gemm_nt(
    const bf16_t* __restrict__ A, const bf16_t* __restrict__ B,
    const float* __restrict__ bias, const bf16_t* __restrict__ mulm,
    const float* __restrict__ res, float* __restrict__ outf,
    bf16_t* __restrict__ outb, int M, int N, int K) {
  __shared__ bf16_t As[128 * 32];
  __shared__ bf16_t Bs[128 * 32];
  const int tid = threadIdx.x;
  const long row0 = (long)blockIdx.y * 128;
  const long col0 = (long)blockIdx.x * 128;
  const int wid = tid >> 6, lane = tid & 63;
  const int wr = (wid >> 1) * 64;
  const int wc = (wid & 1) * 64;
  const int fr = lane & 15, fq = lane >> 4;
  const int srow = tid >> 2;
  const int scol = (tid & 3) * 8;

  f32x4 acc[4][4] = {};

  const bf16_t* Ag = A + (row0 + srow) * (long)K + scol;
  const bf16_t* Bg = B + (col0 + srow) * (long)K + scol;
  const long k64 = 64L * K;
  bf16_t* ldsA = As + wid * 512;
  bf16_t* ldsB = Bs + wid * 512;

  for (int k0 = 0; k0 < K; k0 += 32) {
    GLOAD16(Ag + k0, ldsA);
    GLOAD16(Ag + k0 + k64, ldsA + 2048);
    GLOAD16(Bg + k0, ldsB);
    GLOAD16(Bg + k0 + k64, ldsB + 2048);
    __syncthreads();
    bf16x8 av[4], bv[4];
#pragma unroll
    for (int i = 0; i < 4; i++)
      av[i] = *(const bf16x8*)(As + (wr + i * 16 + fr) * 32 + fq * 8);
#pragma unroll
    for (int j = 0; j < 4; j++)
      bv[j] = *(const bf16x8*)(Bs + (wc + j * 16 + fr) * 32 + fq * 8);
#pragma unroll
    for (int i = 0; i < 4; i++)
#pragma unroll
      for (int j = 0; j < 4; j++)
        acc[i][j] = __builtin_amdgcn_mfma_f32_16x16x32_bf16(av[i], bv[j],
                                                            acc[i][j], 0, 0, 0);
    __syncthreads();
  }

#pragma unroll
  for (int i = 0; i < 4; i++) {
#pragma unroll
    for (int j = 0; j < 4; j++) {
#pragma unroll
      for (int r = 0; r < 4; r++) {
        long gi = row0 + wr + i * 16 + fq * 4 + r;
        long gj = col0 + wc + j * 16 + fr;
        float v = acc[i][j][r];
        if (BIAS == 1) v += bias[gj];
        if (BIAS == 2) v += bias[gi];
        long idx = gi * (long)N + gj;
        if (MUL) v *= (float)mulm[idx];
        if (RES) v += res[idx];
        if (OUTBF16) outb[idx] = (bf16_t)v;
        else outf[idx] = v;
      }
    }
  }
}

// ---------------- row softmax over 8192 cols, bf16 in-place ----------------
__global__ __launch_bounds__(256) void softmax_bf16_inplace(
    bf16_t* __restrict__ buf) {
  const long row = blockIdx.x;
  bf16_t* p = buf + row * 8192;
  const int t = threadIdx.x;
  float v[32];
#pragma unroll
  for (int i = 0; i < 4; i++) {
    bf16x8 raw = *(const bf16x8*)(p + t * 32 + i * 8);
#pragma unroll
    for (int j = 0; j < 8; j++) v[i * 8 + j] = (float)raw[j];
  }
  float m = -1e30f;
#pragma unroll
  for (int i = 0; i < 32; i++) m = fmaxf(m, v[i]);
  for (int off = 32; off; off >>= 1) m = fmaxf(m, __shfl_xor(m, off, 64));
  __shared__ float redm[4], reds[4];
  if ((t & 63) == 0) redm[t >> 6] = m;
  __syncthreads();
  m = fmaxf(fmaxf(redm[0], redm[1]), fmaxf(redm[2], redm[3]));
  float s = 0.f;
#pragma unroll
  for (int i = 0; i < 32; i++) {
    v[i] = __expf(v[i] - m);
    s += v[i];
  }
  for (int off = 32; off; off >>= 1) s += __shfl_xor(s, off, 64);
  if ((t & 63) == 0) reds[t >> 6] = s;
  __syncthreads();
  s = reds[0] + reds[1] + reds[2] + reds[3];
  float inv = 1.0f / s;
#pragma unroll
  for (int i = 0; i < 4; i++) {
    bf16x8 o;
#pragma unroll
    for (int j = 0; j < 8; j++) o[j] = (bf16_t)(v[i * 8 + j] * inv);
    *(bf16x8*)(p + t * 32 + i * 8) = o;
  }
}

// --------- row softmax: bf16 logits in, fp32 out + bf16 in-place ----------
__global__ __launch_bounds__(256) void softmax_f_k(bf16_t* __restrict__ fm,
                                                   float* __restrict__ outf) {
  const long row = blockIdx.x;
  bf16_t* p = fm + row * 8192;
  float* q = outf + row * 8192;
  const int t = threadIdx.x;
  float v[32];
#pragma unroll
  for (int i = 0; i < 4; i++) {
    bf16x8 raw = *(const bf16x8*)(p + t * 32 + i * 8);
#pragma unroll
    for (int j = 0; j < 8; j++) v[i * 8 + j] = (float)raw[j];
  }
  float m = -1e30f;
#pragma unroll
  for (int i = 0; i < 32; i++) m = fmaxf(m, v[i]);
  for (int off = 32; off; off >>= 1) m = fmaxf(m, __shfl_xor(m, off, 64));
  __shared__ float redm[4], reds[4];
  if ((t & 63) == 0) redm[t >> 6] = m;
  __syncthreads();
  m = fmaxf(fmaxf(redm[0], redm[1]), fmaxf(redm[2], redm[3]));
  float s = 0.f;
#pragma unroll
  for (int i = 0; i < 32; i++) {
    v[i] = __expf(v[i] - m);
    s += v[i];
  }
  for (int off = 32; off; off >>= 1) s += __shfl_xor(s, off, 64);
  if ((t & 63) == 0) reds[t >> 6] = s;
  __syncthreads();
  s = reds[0] + reds[1] + reds[2] + reds[3];
  float inv = 1.0f / s;
#pragma unroll
  for (int i = 0; i < 8; i++) {
    float4 o;
    o.x = v[i * 4 + 0] * inv;
    o.y = v[i * 4 + 1] * inv;
    o.z = v[i * 4 + 2] * inv;
    o.w = v[i * 4 + 3] * inv;
    *(float4*)(q + t * 32 + i * 4) = o;
  }
#pragma unroll
  for (int i = 0; i < 4; i++) {
    bf16x8 o;
#pragma unroll
    for (int j = 0; j < 8; j++) o[j] = (bf16_t)(v[i * 8 + j] * inv);
    *(bf16x8*)(p + t * 32 + i * 8) = o;
  }
}

// ---------------------------------------------------------------------------
extern "C" void kernel_launch(void* const* d_in, const int* in_sizes, int n_in,
                              void* d_out, int out_size, void* d_ws,
                              size_t ws_size, hipStream_t stream) {
  const int N = 8192, C = 2048, IC = 1024;
  const float* x = (const float*)d_in[0];
  const float* theta_w = (const float*)d_in[1];
  const float* theta_b = (const float*)d_in[2];
  const float* phi_w = (const float*)d_in[3];
  const float* phi_b = (const float*)d_in[4];
  const float* g_w = (const float*)d_in[5];
  const float* g_b = (const float*)d_in[6];
  const float* W_w = (const float*)d_in[7];
  const float* W_b = (const float*)d_in[8];
  const float* mask_w = (const float*)d_in[9];
  const float* mask_b = (const float*)d_in[10];

  float* z_out = (float*)d_out;            // [N,C] fp32
  float* f_out = z_out + (long)N * C;      // [N,N] fp32

  // d_out-hosted scratch (dead before those regions' final writes):
  bf16_t* ML = (bf16_t*)f_out;             // [N,N] bf16 mask logits -> mask
  bf16_t* th16 = (bf16_t*)z_out;           // [N,IC]
  bf16_t* ph16 = th16 + (long)N * IC;      // [N,IC]
  bf16_t* gT16 = ph16 + (long)N * IC;      // [IC,N]

  char* w = (char*)d_ws;
  bf16_t* xb = (bf16_t*)w;      w += (long)N * C * 2;
  bf16_t* mwb = (bf16_t*)w;     w += (long)N * C * 2;
  bf16_t* thwb = (bf16_t*)w;    w += (long)IC * C * 2;
  bf16_t* phwb = (bf16_t*)w;    w += (long)IC * C * 2;
  bf16_t* gwb = (bf16_t*)w;     w += (long)IC * C * 2;
  bf16_t* Wwb = (bf16_t*)w;     w += (long)C * IC * 2;
  bf16_t* fm = (bf16_t*)w;      w += (long)N * N * 2;   // f*mask logits -> P
  bf16_t* y16 = (bf16_t*)w;     w += (long)N * IC * 2;

  cast_f32_bf16_k<<<8192, 256, 0, stream>>>(x, xb, (long)N * C / 8);
  cast_f32_bf16_k<<<8192, 256, 0, stream>>>(mask_w, mwb, (long)N * C / 8);
  cast_f32_bf16_k<<<1024, 256, 0, stream>>>(theta_w, thwb, (long)IC * C / 8);
  cast_f32_bf16_k<<<1024, 256, 0, stream>>>(phi_w, phwb, (long)IC * C / 8);
  cast_f32_bf16_k<<<1024, 256, 0, stream>>>(g_w, gwb, (long)IC * C / 8);
  cast_f32_bf16_k<<<1024, 256, 0, stream>>>(W_w, Wwb, (long)C * IC / 8);

  // projections (128^2 kernel)
  gemm_nt<1, false, false, true><<<dim3(IC / 128, N / 128), 256, 0, stream>>>(
      xb, thwb, theta_b, nullptr, nullptr, nullptr, th16, N, IC, C);
  gemm_nt<1, false, false, true><<<dim3(IC / 128, N / 128), 256, 0, stream>>>(
      xb, phwb, phi_b, nullptr, nullptr, nullptr, ph16, N, IC, C);
  gemm_nt<2, false, false, true><<<dim3(N / 128, IC / 128), 256, 0, stream>>>(
      gwb, xb, g_b, nullptr, nullptr, nullptr, gT16, IC, N, C);
  // mask logits (256^2 pipelined kernel), bias per col
  gemm256<1, false><<<dim3(N / 256, N / 256), 512, 0, stream>>>(
      xb, mwb, mask_b, nullptr, ML, N, N, C);
  softmax_bf16_inplace<<<N, 256, 0, stream>>>(ML);
  // f*mask logits (256^2 pipelined kernel)
  gemm256<0, true><<<dim3(N / 256, N / 256), 512, 0, stream>>>(
      th16, ph16, nullptr, ML, fm, N, N, IC);
  softmax_f_k<<<N, 256, 0, stream>>>(fm, f_out);
  // y = P @ g_x (NT via gT16)
  gemm_nt<0, false, false, true><<<dim3(IC / 128, N / 128), 256, 0, stream>>>(
      fm, gT16, nullptr, nullptr, nullptr, nullptr, y16, N, IC, N);
  // z = y @ W_w^T + W_b + x
  gemm_nt<1, false, true, false><<<dim3(C / 128, N / 128), 256, 0, stream>>>(
      y16, Wwb, W_b, nullptr, x, z_out, nullptr, N, C, IC);
}

// Round 3
// 1205.096 us; speedup vs baseline: 1.1345x; 1.0102x over previous
//
#include <hip/hip_runtime.h>
#include <hip/hip_bf16.h>

typedef __bf16 bf16_t;
typedef __bf16 bf16x8 __attribute__((ext_vector_type(8)));
typedef float f32x4 __attribute__((ext_vector_type(4)));

#define GLOAD16(gp, lp) __builtin_amdgcn_global_load_lds(                      \
    (const __attribute__((address_space(1))) void*)(gp),                       \
    (__attribute__((address_space(3))) void*)(lp), 16, 0, 0)
#define BARRIER() asm volatile("s_barrier" ::: "memory")
#define LGKM0()                                                                \
  do {                                                                         \
    asm volatile("s_waitcnt lgkmcnt(0)" ::: "memory");                         \
    __builtin_amdgcn_sched_barrier(0);                                         \
  } while (0)

// ---------------- cast fp32 -> bf16 (vectorized x8) ----------------
__global__ __launch_bounds__(256) void cast_f32_bf16_k(
    const float* __restrict__ in, bf16_t* __restrict__ out, long n8) {
  long i = (long)blockIdx.x * blockDim.x + threadIdx.x;
  long stride = (long)gridDim.x * blockDim.x;
  for (; i < n8; i += stride) {
    long e = i * 8;
    float4 a = *(const float4*)(in + e);
    float4 b = *(const float4*)(in + e + 4);
    bf16x8 o;
    o[0] = (__bf16)a.x; o[1] = (__bf16)a.y; o[2] = (__bf16)a.z; o[3] = (__bf16)a.w;
    o[4] = (__bf16)b.x; o[5] = (__bf16)b.y; o[6] = (__bf16)b.z; o[7] = (__bf16)b.w;
    *(bf16x8*)(out + e) = o;
  }
}

// ============ 256x256-tile 8-wave GEMM, BK=32, 4-deep counted-vmcnt pipeline
// LDS rows are 64B; 16B slot XOR-swizzled by (row>>1)&3 (2-way = free).
// global_load_lds writes linearly -> inverse swizzle on the GLOBAL source.
template <int VM, bool ST>
__device__ __forceinline__ void kstep256(
    int t, char* lds, const int (&aoff)[8], const int (&boff)[4],
    const bf16_t* As0, const bf16_t* As1, const bf16_t* Bs0,
    const bf16_t* Bs1, int dst0, int dst1, f32x4 (&acc)[8][4]) {
  char* buf = lds + (t & 3) * 32768;
  char* nbuf = lds + ((t + 3) & 3) * 32768;
  bf16x8 av[8], bv[4];
  // ---- phase 1: 8 ds_read + stage A(t+3) + 16 MFMA (row frags 0..3)
#pragma unroll
  for (int i = 0; i < 4; ++i) av[i] = *(const bf16x8*)(buf + aoff[i]);
#pragma unroll
  for (int j = 0; j < 4; ++j) bv[j] = *(const bf16x8*)(buf + 16384 + boff[j]);
  if (ST) {
    GLOAD16(As0 + (long)(t + 3) * 32, nbuf + dst0);
    GLOAD16(As1 + (long)(t + 3) * 32, nbuf + dst1);
  }
  BARRIER();
  LGKM0();
  __builtin_amdgcn_s_setprio(1);
#pragma unroll
  for (int i = 0; i < 4; ++i)
#pragma unroll
    for (int j = 0; j < 4; ++j)
      acc[i][j] = __builtin_amdgcn_mfma_f32_16x16x32_bf16(av[i], bv[j],
                                                          acc[i][j], 0, 0, 0);
  __builtin_amdgcn_s_setprio(0);
  BARRIER();
  // ---- phase 2: 4 ds_read + stage B(t+3) + counted vmcnt + 16 MFMA (4..7)
#pragma unroll
  for (int i = 4; i < 8; ++i) av[i] = *(const bf16x8*)(buf + aoff[i]);
  if (ST) {
    GLOAD16(Bs0 + (long)(t + 3) * 32, nbuf + 16384 + dst0);
    GLOAD16(Bs1 + (long)(t + 3) * 32, nbuf + 16384 + dst1);
  }
  if (VM == 8) asm volatile("s_waitcnt vmcnt(8)" ::: "memory");
  else if (VM == 4) asm volatile("s_waitcnt vmcnt(4)" ::: "memory");
  else if (VM == 0) asm volatile("s_waitcnt vmcnt(0)" ::: "memory");
  BARRIER();
  LGKM0();
  __builtin_amdgcn_s_setprio(1);
#pragma unroll
  for (int i = 4; i < 8; ++i)
#pragma unroll
    for (int j = 0; j < 4; ++j)
      acc[i][j] = __builtin_amdgcn_mfma_f32_16x16x32_bf16(av[i], bv[j],
                                                          acc[i][j], 0, 0, 0);
  __builtin_amdgcn_s_setprio(0);
  BARRIER();
}

template <int BIAS, bool MUL>
__global__ __launch_bounds__(512, 2) void gemm256(
    const bf16_t* __restrict__ A, const bf16_t* __restrict__ B,
    const float* __restrict__ bias, const bf16_t* __restrict__ mulm,
    bf16_t* __restrict__ out, int M, int N, int K) {
  __shared__ __align__(1024) char lds[131072];
  const int tid = threadIdx.x;
  const int gx = N >> 8;
  int bid = blockIdx.y * gx + blockIdx.x;
  const int nwg = gridDim.x * gridDim.y;        // multiple of 8 for our shapes
  const int cpx = nwg >> 3;
  bid = (bid & 7) * cpx + (bid >> 3);           // XCD-aware bijective swizzle
  const long row0 = (long)(bid / gx) * 256;
  const long col0 = (long)(bid % gx) * 256;

  const int w = tid >> 6, lane = tid & 63;
  const int wm = w >> 2, wn = w & 3;            // 2M x 4N waves
  const int fr = lane & 15, fq = lane >> 4;
  const int sx = (fr >> 1) & 3;                 // read-side swizzle (lane-const)

  // LDS byte offsets of this thread's fragments (row stride 64B, BK=32)
  int aoff[8], boff[4];
#pragma unroll
  for (int i = 0; i < 8; ++i)
    aoff[i] = (wm * 128 + i * 16 + fr) * 64 + ((fq ^ sx) << 4);
#pragma unroll
  for (int j = 0; j < 4; ++j)
    boff[j] = (wn * 64 + j * 16 + fr) * 64 + ((fq ^ sx) << 4);

  // staging: linear LDS dest; inverse-swizzled global k-chunk per phys slot
  const int p0 = w * 1024 + lane * 16;          // physical byte in 16KB tile
  const int p1 = p0 + 8192;
  const int r0 = p0 >> 6, r1 = p1 >> 6;
  const int s0 = ((p0 >> 4) & 3) ^ ((r0 >> 1) & 3);
  const int s1 = ((p1 >> 4) & 3) ^ ((r1 >> 1) & 3);
  const bf16_t* As0 = A + (row0 + r0) * (long)K + (s0 << 3);
  const bf16_t* As1 = A + (row0 + r1) * (long)K + (s1 << 3);
  const bf16_t* Bs0 = B + (col0 + r0) * (long)K + (s0 << 3);
  const bf16_t* Bs1 = B + (col0 + r1) * (long)K + (s1 << 3);
  const int dst0 = w * 1024;                    // wave-uniform LDS dest base
  const int dst1 = dst0 + 8192;

  f32x4 acc[8][4] = {};
  const int NT = K >> 5;

  // prologue: stage tiles 0,1,2 (12 VMEM/wave), wait for tile 0 (vmcnt 8)
#pragma unroll
  for (int t = 0; t < 3; ++t) {
    char* buf = lds + t * 32768;
    GLOAD16(As0 + (long)t * 32, buf + dst0);
    GLOAD16(As1 + (long)t * 32, buf + dst1);
    GLOAD16(Bs0 + (long)t * 32, buf + 16384 + dst0);
    GLOAD16(Bs1 + (long)t * 32, buf + 16384 + dst1);
  }
  asm volatile("s_waitcnt vmcnt(8)" ::: "memory");
  BARRIER();

  int t = 0;
  for (; t < NT - 3; ++t)
    kstep256<8, true>(t, lds, aoff, boff, As0, As1, Bs0, Bs1, dst0, dst1, acc);
  kstep256<4, false>(t, lds, aoff, boff, As0, As1, Bs0, Bs1, dst0, dst1, acc); ++t;
  kstep256<0, false>(t, lds, aoff, boff, As0, As1, Bs0, Bs1, dst0, dst1, acc); ++t;
  kstep256<-1, false>(t, lds, aoff, boff, As0, As1, Bs0, Bs1, dst0, dst1, acc);

  // epilogue: C/D layout col=lane&15, row=(lane>>4)*4+r
#pragma unroll
  for (int i = 0; i < 8; ++i)
#pragma unroll
    for (int j = 0; j < 4; ++j)
#pragma unroll
      for (int r = 0; r < 4; ++r) {
        long gi = row0 + wm * 128 + i * 16 + fq * 4 + r;
        long gj = col0 + wn * 64 + j * 16 + fr;
        float v = acc[i][j][r];
        if (BIAS == 1) v += bias[gj];
        long idx = gi * (long)N + gj;
        if (MUL) v *= (float)mulm[idx];
        out[idx] = (bf16_t)v;
      }
}

// ---------------- NT GEMM (m97 128x128), same swizzle ----------------------
template <int BIAS, bool MUL, bool RES, bool OUTBF16>
__global__ __launch_bounds__(256) void gemm_nt(
    const bf16_t* __restrict__ A, const bf16_t* __restrict__ B,
    const float* __restrict__ bias, const bf16_t* __restrict__ mulm,
    const float* __restrict__ res, float* __restrict__ outf,
    bf16_t* __restrict__ outb, int M, int N, int K) {
  __shared__ bf16_t As[128 * 32];
  __shared__ bf16_t Bs[128 * 32];
  const int tid = threadIdx.x;
  const long row0 = (long)blockIdx.y * 128;
  const long col0 = (long)blockIdx.x * 128;
  const int wid = tid >> 6, lane = tid & 63;
  const int wr = (wid >> 1) * 64;
  const int wc = (wid & 1) * 64;
  const int fr = lane & 15, fq = lane >> 4;
  const int sx = (fr >> 1) & 3;
  const int srow = tid >> 2;
  const int scol = ((tid & 3) ^ ((srow >> 1) & 3)) * 8;  // inverse-swz source

  f32x4 acc[4][4] = {};

  const bf16_t* Ag = A + (row0 + srow) * (long)K + scol;
  const bf16_t* Bg = B + (col0 + srow) * (long)K + scol;
  const long k64 = 64L * K;
  bf16_t* ldsA = As + wid * 512;
  bf16_t* ldsB = Bs + wid * 512;

  for (int k0 = 0; k0 < K; k0 += 32) {
    GLOAD16(Ag + k0, ldsA);
    GLOAD16(Ag + k0 + k64, ldsA + 2048);
    GLOAD16(Bg + k0, ldsB);
    GLOAD16(Bg + k0 + k64, ldsB + 2048);
    __syncthreads();
    bf16x8 av[4], bv[4];
#pragma unroll
    for (int i = 0; i < 4; i++)
      av[i] = *(const bf16x8*)(As + (wr + i * 16 + fr) * 32 + ((fq ^ sx) << 3));
#pragma unroll
    for (int j = 0; j < 4; j++)
      bv[j] = *(const bf16x8*)(Bs + (wc + j * 16 + fr) * 32 + ((fq ^ sx) << 3));
#pragma unroll
    for (int i = 0; i < 4; i++)
#pragma unroll
      for (int j = 0; j < 4; j++)
        acc[i][j] = __builtin_amdgcn_mfma_f32_16x16x32_bf16(av[i], bv[j],
                                                            acc[i][j], 0, 0, 0);
    __syncthreads();
  }

#pragma unroll
  for (int i = 0; i < 4; i++) {
#pragma unroll
    for (int j = 0; j < 4; j++) {
#pragma unroll
      for (int r = 0; r < 4; r++) {
        long gi = row0 + wr + i * 16 + fq * 4 + r;
        long gj = col0 + wc + j * 16 + fr;
        float v = acc[i][j][r];
        if (BIAS == 1) v += bias[gj];
        if (BIAS == 2) v += bias[gi];
        long idx = gi * (long)N + gj;
        if (MUL) v *= (float)mulm[idx];
        if (RES) v += res[idx];
        if (OUTBF16) outb[idx] = (bf16_t)v;
        else outf[idx] = v;
      }
    }
  }
}

// ---------------- row softmax over 8192 cols, bf16 in-place ----------------
__global__ __launch_bounds__(256) void softmax_bf16_inplace(
    bf16_t* __restrict__ buf) {
  const long row = blockIdx.x;
  bf16_t* p = buf + row * 8192;
  const int t = threadIdx.x;
  float v[32];
#pragma unroll
  for (int i = 0; i < 4; i++) {
    bf16x8 raw = *(const bf16x8*)(p + t * 32 + i * 8);
#pragma unroll
    for (int j = 0; j < 8; j++) v[i * 8 + j] = (float)raw[j];
  }
  float m = -1e30f;
#pragma unroll
  for (int i = 0; i < 32; i++) m = fmaxf(m, v[i]);
  for (int off = 32; off; off >>= 1) m = fmaxf(m, __shfl_xor(m, off, 64));
  __shared__ float redm[4], reds[4];
  if ((t & 63) == 0) redm[t >> 6] = m;
  __syncthreads();
  m = fmaxf(fmaxf(redm[0], redm[1]), fmaxf(redm[2], redm[3]));
  float s = 0.f;
#pragma unroll
  for (int i = 0; i < 32; i++) {
    v[i] = __expf(v[i] - m);
    s += v[i];
  }
  for (int off = 32; off; off >>= 1) s += __shfl_xor(s, off, 64);
  if ((t & 63) == 0) reds[t >> 6] = s;
  __syncthreads();
  s = reds[0] + reds[1] + reds[2] + reds[3];
  float inv = 1.0f / s;
#pragma unroll
  for (int i = 0; i < 4; i++) {
    bf16x8 o;
#pragma unroll
    for (int j = 0; j < 8; j++) o[j] = (bf16_t)(v[i * 8 + j] * inv);
    *(bf16x8*)(p + t * 32 + i * 8) = o;
  }
}

// --------- row softmax: bf16 logits in, fp32 out + bf16 in-place ----------
__global__ __launch_bounds__(256) void softmax_f_k(bf16_t* __restrict__ fm,
                                                   float* __restrict__ outf) {
  const long row = blockIdx.x;
  bf16_t* p = fm + row * 8192;
  float* q = outf + row * 8192;
  const int t = threadIdx.x;
  float v[32];
#pragma unroll
  for (int i = 0; i < 4; i++) {
    bf16x8 raw = *(const bf16x8*)(p + t * 32 + i * 8);
#pragma unroll
    for (int j = 0; j < 8; j++) v[i * 8 + j] = (float)raw[j];
  }
  float m = -1e30f;
#pragma unroll
  for (int i = 0; i < 32; i++) m = fmaxf(m, v[i]);
  for (int off = 32; off; off >>= 1) m = fmaxf(m, __shfl_xor(m, off, 64));
  __shared__ float redm[4], reds[4];
  if ((t & 63) == 0) redm[t >> 6] = m;
  __syncthreads();
  m = fmaxf(fmaxf(redm[0], redm[1]), fmaxf(redm[2], redm[3]));
  float s = 0.f;
#pragma unroll
  for (int i = 0; i < 32; i++) {
    v[i] = __expf(v[i] - m);
    s += v[i];
  }
  for (int off = 32; off; off >>= 1) s += __shfl_xor(s, off, 64);
  if ((t & 63) == 0) reds[t >> 6] = s;
  __syncthreads();
  s = reds[0] + reds[1] + reds[2] + reds[3];
  float inv = 1.0f / s;
#pragma unroll
  for (int i = 0; i < 8; i++) {
    float4 o;
    o.x = v[i * 4 + 0] * inv;
    o.y = v[i * 4 + 1] * inv;
    o.z = v[i * 4 + 2] * inv;
    o.w = v[i * 4 + 3] * inv;
    *(float4*)(q + t * 32 + i * 4) = o;
  }
#pragma unroll
  for (int i = 0; i < 4; i++) {
    bf16x8 o;
#pragma unroll
    for (int j = 0; j < 8; j++) o[j] = (bf16_t)(v[i * 8 + j] * inv);
    *(bf16x8*)(p + t * 32 + i * 8) = o;
  }
}

// ---------------------------------------------------------------------------
extern "C" void kernel_launch(void* const* d_in, const int* in_sizes, int n_in,
                              void* d_out, int out_size, void* d_ws,
                              size_t ws_size, hipStream_t stream) {
  const int N = 8192, C = 2048, IC = 1024;
  const float* x = (const float*)d_in[0];
  const float* theta_w = (const float*)d_in[1];
  const float* theta_b = (const float*)d_in[2];
  const float* phi_w = (const float*)d_in[3];
  const float* phi_b = (const float*)d_in[4];
  const float* g_w = (const float*)d_in[5];
  const float* g_b = (const float*)d_in[6];
  const float* W_w = (const float*)d_in[7];
  const float* W_b = (const float*)d_in[8];
  const float* mask_w = (const float*)d_in[9];
  const float* mask_b = (const float*)d_in[10];

  float* z_out = (float*)d_out;            // [N,C] fp32
  float* f_out = z_out + (long)N * C;      // [N,N] fp32

  // d_out-hosted scratch (dead before those regions' final writes):
  bf16_t* ML = (bf16_t*)f_out;             // [N,N] bf16 mask logits -> mask
  bf16_t* th16 = (bf16_t*)z_out;           // [N,IC]
  bf16_t* ph16 = th16 + (long)N * IC;      // [N,IC]
  bf16_t* gT16 = ph16 + (long)N * IC;      // [IC,N]

  char* w = (char*)d_ws;
  bf16_t* xb = (bf16_t*)w;      w += (long)N * C * 2;
  bf16_t* mwb = (bf16_t*)w;     w += (long)N * C * 2;
  bf16_t* thwb = (bf16_t*)w;    w += (long)IC * C * 2;
  bf16_t* phwb = (bf16_t*)w;    w += (long)IC * C * 2;
  bf16_t* gwb = (bf16_t*)w;     w += (long)IC * C * 2;
  bf16_t* Wwb = (bf16_t*)w;     w += (long)C * IC * 2;
  bf16_t* fm = (bf16_t*)w;      w += (long)N * N * 2;   // f*mask logits -> P
  bf16_t* y16 = (bf16_t*)w;     w += (long)N * IC * 2;

  cast_f32_bf16_k<<<8192, 256, 0, stream>>>(x, xb, (long)N * C / 8);
  cast_f32_bf16_k<<<8192, 256, 0, stream>>>(mask_w, mwb, (long)N * C / 8);
  cast_f32_bf16_k<<<1024, 256, 0, stream>>>(theta_w, thwb, (long)IC * C / 8);
  cast_f32_bf16_k<<<1024, 256, 0, stream>>>(phi_w, phwb, (long)IC * C / 8);
  cast_f32_bf16_k<<<1024, 256, 0, stream>>>(g_w, gwb, (long)IC * C / 8);
  cast_f32_bf16_k<<<1024, 256, 0, stream>>>(W_w, Wwb, (long)C * IC / 8);

  // projections (128^2 kernel)
  gemm_nt<1, false, false, true><<<dim3(IC / 128, N / 128), 256, 0, stream>>>(
      xb, thwb, theta_b, nullptr, nullptr, nullptr, th16, N, IC, C);
  gemm_nt<1, false, false, true><<<dim3(IC / 128, N / 128), 256, 0, stream>>>(
      xb, phwb, phi_b, nullptr, nullptr, nullptr, ph16, N, IC, C);
  gemm_nt<2, false, false, true><<<dim3(N / 128, IC / 128), 256, 0, stream>>>(
      gwb, xb, g_b, nullptr, nullptr, nullptr, gT16, IC, N, C);
  // mask logits (256^2 pipelined kernel), bias per col
  gemm256<1, false><<<dim3(N / 256, N / 256), 512, 0, stream>>>(
      xb, mwb, mask_b, nullptr, ML, N, N, C);
  softmax_bf16_inplace<<<N, 256, 0, stream>>>(ML);
  // f*mask logits (256^2 pipelined kernel)
  gemm256<0, true><<<dim3(N / 256, N / 256), 512, 0, stream>>>(
      th16, ph16, nullptr, ML, fm, N, N, IC);
  softmax_f_k<<<N, 256, 0, stream>>>(fm, f_out);
  // y = P @ g_x (NT via gT16)
  gemm_nt<0, false, false, true><<<dim3(IC / 128, N / 128), 256, 0, stream>>>(
      fm, gT16, nullptr, nullptr, nullptr, nullptr, y16, N, IC, N);
  // z = y @ W_w^T + W_b + x
  gemm_nt<1, false, true, false><<<dim3(C / 128, N / 128), 256, 0, stream>>>(
      y16, Wwb, W_b, nullptr, x, z_out, nullptr, N, C, IC);
}